// Round 1
// baseline (438.787 us; speedup 1.0000x reference)
//
#include <hip/hip_runtime.h>
#include <hip/hip_bf16.h>

typedef __bf16 bf16_t;
typedef __attribute__((ext_vector_type(8))) __bf16 bf16x8;
typedef __attribute__((ext_vector_type(4))) __bf16 bf16x4;
typedef __attribute__((ext_vector_type(4))) float floatx4;
typedef __attribute__((ext_vector_type(4))) int intx4;

#define NN 8192
#define FIN 256
#define FOUT 64
#define GAT_ALPHA 0.2f
#define NSLICE 8
#define JS (NN / NSLICE)   // 1024 j's per slice

// ---------------------------------------------------------------------------
// Kernel A: h = input @ W (fp32 in -> bf16 MFMA), store hT (bf16 [64][8192])
// and per-row scalars s1,s2 (fp32), E=exp(s), F=exp(0.2 s).  (unchanged)
// ---------------------------------------------------------------------------
__global__ __launch_bounds__(256) void gat_h_kernel(
    const float* __restrict__ input,    // [8192][256] fp32
    const float* __restrict__ W,        // [256][64] fp32
    const float* __restrict__ a,        // [128] fp32
    bf16_t* __restrict__ hT,            // [64][8192] bf16 (internal)
    float* __restrict__ s1g, float* __restrict__ e1g, float* __restrict__ f1g,
    float* __restrict__ s2g, float* __restrict__ e2g, float* __restrict__ f2g)
{
    alignas(16) __shared__ bf16_t in_lds[32][264];  // input tile, K contiguous
    alignas(16) __shared__ bf16_t wt_lds[64][264];  // W transposed [f][k]
    __shared__ float h_lds[32][65];                 // h tile fp32 for s1/s2

    const int t  = threadIdx.x;
    const int i0 = blockIdx.x * 32;

    // stage input tile [32][256]: fp32 float4 loads -> bf16x4 LDS stores
    #pragma unroll
    for (int v = 0; v < 8; v++) {
        int u  = v * 256 + t;          // 0..2047
        int i  = u >> 6;               // 0..31
        int k4 = (u & 63) * 4;         // 0..252
        floatx4 x = *(const floatx4*)(input + (size_t)(i0 + i) * FIN + k4);
        bf16x4 b;
        #pragma unroll
        for (int e = 0; e < 4; e++) b[e] = (bf16_t)x[e];
        *(bf16x4*)(&in_lds[i][k4]) = b;
    }
    // stage W transposed: read [k][f] coalesced fp32, write wt_lds[f][k] bf16
    #pragma unroll
    for (int v = 0; v < 16; v++) {
        int u  = v * 256 + t;          // 0..4095
        int k  = u >> 4;               // 0..255
        int f4 = (u & 15) * 4;         // 0..60
        floatx4 wv = *(const floatx4*)(W + k * FOUT + f4);
        #pragma unroll
        for (int e = 0; e < 4; e++) wt_lds[f4 + e][k] = (bf16_t)wv[e];
    }
    __syncthreads();

    const int wave = t >> 6;
    const int lane = t & 63;
    const int i16  = (wave & 1) * 16;
    const int f32  = (wave >> 1) * 32;
    const int lm   = lane & 15;
    const int lq   = lane >> 4;

    floatx4 acc0 = {0.f, 0.f, 0.f, 0.f};
    floatx4 acc1 = {0.f, 0.f, 0.f, 0.f};
    #pragma unroll
    for (int ks = 0; ks < 8; ks++) {
        int ko = ks * 32 + lq * 8;
        bf16x8 af = *(const bf16x8*)(&in_lds[i16 + lm][ko]);
        bf16x8 b0 = *(const bf16x8*)(&wt_lds[f32 + lm][ko]);
        bf16x8 b1 = *(const bf16x8*)(&wt_lds[f32 + 16 + lm][ko]);
        acc0 = __builtin_amdgcn_mfma_f32_16x16x32_bf16(af, b0, acc0, 0, 0, 0);
        acc1 = __builtin_amdgcn_mfma_f32_16x16x32_bf16(af, b1, acc1, 0, 0, 0);
    }

    // store hT (bf16): C layout col=lane&15 (=f), row=lq*4+r (=i within 16)
    #pragma unroll
    for (int c = 0; c < 2; c++) {
        floatx4 acc = c ? acc1 : acc0;
        int f  = f32 + c * 16 + lm;
        int ib = i0 + i16 + lq * 4;
        bf16x4 hp;
        #pragma unroll
        for (int r = 0; r < 4; r++) hp[r] = (bf16_t)acc[r];
        *(bf16x4*)(hT + (size_t)f * NN + ib) = hp;
    }
    // fp32 h tile into LDS for s1/s2
    #pragma unroll
    for (int c = 0; c < 2; c++) {
        floatx4 acc = c ? acc1 : acc0;
        #pragma unroll
        for (int r = 0; r < 4; r++)
            h_lds[i16 + lq * 4 + r][f32 + c * 16 + lm] = acc[r];
    }
    __syncthreads();

    if (t < 64) {
        int r   = t & 31;
        int sel = t >> 5;                       // 0 -> a1/s1, 1 -> a2/s2
        const float* av = a + sel * FOUT;
        float s = 0.f;
        #pragma unroll 8
        for (int f = 0; f < FOUT; f++) s += h_lds[r][f] * av[f];
        int gi = i0 + r;
        float E = expf(s);
        float F = expf(GAT_ALPHA * s);
        if (sel == 0) { s1g[gi] = s; e1g[gi] = E; f1g[gi] = F; }
        else          { s2g[gi] = s; e2g[gi] = E; f2g[gi] = F; }
    }
}

// ---------------------------------------------------------------------------
// Kernel B (rewritten): barrier-free, wave-independent attention+aggregation.
// Each wave owns 16 i-rows and a 1024-j slice. adj + hT loaded straight to
// registers (no LDS staging, no per-iteration __syncthreads); w computed
// in-register as A-fragment: w = adj ? max(E1*e2, F1*f2) : 0
// (exp(leaky_relu(s)) == max(exp(s), exp(0.2 s)) by monotonicity of exp).
// Rowsum accumulated by a 5th MFMA against an all-ones B fragment.
// Grid (128, NSLICE) = 1024 blocks = 4 blocks/CU, 16 waves/CU.
// ---------------------------------------------------------------------------
#define LOADB(B, J)                                                           \
    {                                                                         \
        B##a0 = *(const intx4*)(adjp + (J));                                  \
        B##a1 = *(const intx4*)(adjp + (J) + 4);                              \
        B##h0 = *(const bf16x8*)(hp + (size_t)0  * NN + (J));                 \
        B##h1 = *(const bf16x8*)(hp + (size_t)16 * NN + (J));                 \
        B##h2 = *(const bf16x8*)(hp + (size_t)32 * NN + (J));                 \
        B##h3 = *(const bf16x8*)(hp + (size_t)48 * NN + (J));                 \
    }

#define COMP(B, JL)                                                           \
    {                                                                         \
        int oo = (JL) + lq * 8;                                               \
        floatx4 e2a = *(const floatx4*)(&e2l[oo]);                            \
        floatx4 e2b = *(const floatx4*)(&e2l[oo + 4]);                        \
        floatx4 f2a = *(const floatx4*)(&f2l[oo]);                            \
        floatx4 f2b = *(const floatx4*)(&f2l[oo + 4]);                        \
        bf16x8 frag;                                                          \
        _Pragma("unroll")                                                     \
        for (int e = 0; e < 4; e++) {                                         \
            float w0 = fmaxf(E1 * e2a[e], F1 * f2a[e]);                       \
            w0 = (B##a0[e] > 0) ? w0 : 0.f;                                   \
            frag[e] = (bf16_t)w0;                                             \
            float w1 = fmaxf(E1 * e2b[e], F1 * f2b[e]);                       \
            w1 = (B##a1[e] > 0) ? w1 : 0.f;                                   \
            frag[e + 4] = (bf16_t)w1;                                         \
        }                                                                     \
        acc0 = __builtin_amdgcn_mfma_f32_16x16x32_bf16(frag, B##h0, acc0,0,0,0); \
        acc1 = __builtin_amdgcn_mfma_f32_16x16x32_bf16(frag, B##h1, acc1,0,0,0); \
        acc2 = __builtin_amdgcn_mfma_f32_16x16x32_bf16(frag, B##h2, acc2,0,0,0); \
        acc3 = __builtin_amdgcn_mfma_f32_16x16x32_bf16(frag, B##h3, acc3,0,0,0); \
        accR = __builtin_amdgcn_mfma_f32_16x16x32_bf16(frag, ones, accR,0,0,0);  \
    }

__global__ __launch_bounds__(256, 4) void gat_att_kernel(
    const int* __restrict__ adj,        // [8192][8192] int32
    const bf16_t* __restrict__ hT,      // [64][8192] bf16
    const float* __restrict__ e1g, const float* __restrict__ f1g,
    const float* __restrict__ e2g, const float* __restrict__ f2g,
    float* __restrict__ pacc,           // [NSLICE][8192][64] fp32 partial acc
    float* __restrict__ prs)            // [NSLICE][8192] fp32 partial rowsum
{
    __shared__ float e2l[JS];
    __shared__ float f2l[JS];

    const int t     = threadIdx.x;
    const int i0    = blockIdx.x * 64;
    const int slice = blockIdx.y;
    const int jbase = slice * JS;

    // stage e2/f2 slice (8 KB) -- the only LDS, the only barrier
    {
        int o = t * 4;
        *(floatx4*)(&e2l[o]) = *(const floatx4*)(e2g + jbase + o);
        *(floatx4*)(&f2l[o]) = *(const floatx4*)(f2g + jbase + o);
    }
    __syncthreads();

    const int wave = t >> 6;
    const int lane = t & 63;
    const int lm   = lane & 15;
    const int lq   = lane >> 4;
    const int row  = i0 + wave * 16 + lm;   // the single i-row this lane owns

    const float E1 = e1g[row];
    const float F1 = f1g[row];

    const int*    adjp = adj + (size_t)row * NN + jbase + lq * 8;
    const bf16_t* hp   = hT + (size_t)lm * NN + jbase + lq * 8;

    floatx4 acc0 = {0.f,0.f,0.f,0.f}, acc1 = {0.f,0.f,0.f,0.f};
    floatx4 acc2 = {0.f,0.f,0.f,0.f}, acc3 = {0.f,0.f,0.f,0.f};
    floatx4 accR = {0.f,0.f,0.f,0.f};

    bf16x8 ones;
    #pragma unroll
    for (int e = 0; e < 8; e++) ones[e] = (bf16_t)1.0f;

    intx4 Xa0, Xa1; bf16x8 Xh0, Xh1, Xh2, Xh3;
    intx4 Ya0, Ya1; bf16x8 Yh0, Yh1, Yh2, Yh3;

    LOADB(X, 0);
    for (int jl = 0; jl < JS; jl += 64) {
        int jn1 = jl + 32;                          // always < JS
        LOADB(Y, jn1);
        COMP(X, jl);
        int jn2 = (jl + 64 < JS) ? (jl + 64) : 0;   // wrap: harmless re-read
        LOADB(X, jn2);
        COMP(Y, jn1);
    }

    // rowsum: accR[r] = full slice rowsum of row (wave*16 + lq*4 + r),
    // identical across all lm lanes -> lm==0 lanes write.
    if (lm == 0) {
        #pragma unroll
        for (int r = 0; r < 4; r++)
            prs[(size_t)slice * NN + i0 + wave * 16 + lq * 4 + r] = accR[r];
    }

    // partial acc: D layout col = c*16 + lm, row = lq*4 + r
    float* pa = pacc + (size_t)slice * NN * FOUT + (size_t)(i0 + wave * 16) * FOUT;
    #pragma unroll
    for (int c = 0; c < 4; c++) {
        floatx4 acc = (c == 0) ? acc0 : (c == 1) ? acc1 : (c == 2) ? acc2 : acc3;
        #pragma unroll
        for (int r = 0; r < 4; r++)
            pa[(size_t)(lq * 4 + r) * FOUT + c * 16 + lm] = acc[r];
    }
}

// ---------------------------------------------------------------------------
// Kernel C: combine NSLICE partials, normalize, ELU, store fp32 output.
// ---------------------------------------------------------------------------
__global__ __launch_bounds__(256) void gat_combine_kernel(
    const float* __restrict__ pacc,     // [NSLICE][8192][64]
    const float* __restrict__ prs,      // [NSLICE][8192]
    float* __restrict__ out)            // [8192][64]
{
    int idx = blockIdx.x * 256 + threadIdx.x;   // one float4 group each
    int i   = idx >> 4;                          // row (16 groups per row)
    floatx4 s = {0.f, 0.f, 0.f, 0.f};
    float rs  = 0.f;
    #pragma unroll
    for (int p = 0; p < NSLICE; p++) {
        floatx4 v = *(const floatx4*)(pacc + (size_t)p * NN * FOUT + (size_t)idx * 4);
        s += v;
        rs += prs[p * NN + i];
    }
    float rinv = (rs > 0.f) ? 1.0f / rs : 0.f;
    floatx4 r;
    #pragma unroll
    for (int e = 0; e < 4; e++) {
        float x = s[e] * rinv;
        r[e] = (x > 0.f) ? x : (expf(x) - 1.0f);
    }
    *(floatx4*)(out + (size_t)idx * 4) = r;
}

// ---------------------------------------------------------------------------
extern "C" void kernel_launch(void* const* d_in, const int* in_sizes, int n_in,
                              void* d_out, int out_size, void* d_ws, size_t ws_size,
                              hipStream_t stream) {
    const float* input = (const float*)d_in[0];     // [8192][256] fp32
    const int*   adj   = (const int*)d_in[1];       // [8192][8192] int32
    const float* W     = (const float*)d_in[2];     // [256][64] fp32
    const float* a     = (const float*)d_in[3];     // [128] fp32
    float*       out   = (float*)d_out;             // [8192][64] fp32

    char* ws = (char*)d_ws;
    bf16_t* hT  = (bf16_t*)ws;                      // 64*8192*2 = 1 MiB
    float*  s1g = (float*)(ws + (1 << 20));
    float*  e1g = s1g + NN;
    float*  f1g = e1g + NN;
    float*  s2g = f1g + NN;
    float*  e2g = s2g + NN;
    float*  f2g = e2g + NN;
    float*  pacc = f2g + NN;                        // NSLICE*8192*64 fp32 = 16 MiB
    float*  prs  = pacc + (size_t)NSLICE * NN * FOUT;  // NSLICE*8192 fp32

    gat_h_kernel<<<NN / 32, 256, 0, stream>>>(input, W, a, hT,
                                              s1g, e1g, f1g, s2g, e2g, f2g);
    dim3 gridB(NN / 64, NSLICE);
    gat_att_kernel<<<gridB, 256, 0, stream>>>(adj, hT, e1g, f1g, e2g, f2g,
                                              pacc, prs);
    gat_combine_kernel<<<NN * FOUT / 4 / 256, 256, 0, stream>>>(pacc, prs, out);
}

// Round 2
// 398.483 us; speedup vs baseline: 1.1011x; 1.1011x over previous
//
#include <hip/hip_runtime.h>
#include <hip/hip_bf16.h>

typedef __bf16 bf16_t;
typedef __attribute__((ext_vector_type(8))) __bf16 bf16x8;
typedef __attribute__((ext_vector_type(4))) __bf16 bf16x4;
typedef __attribute__((ext_vector_type(4))) float floatx4;
typedef __attribute__((ext_vector_type(4))) int intx4;

#define NN 8192
#define FIN 256
#define FOUT 64
#define GAT_ALPHA 0.2f
#define NSLICE 16
#define JS (NN / NSLICE)    // 512 j per slice
#define NCH (JS / 64)       // 8 chunks of 64 j

// global_load_lds: wave-uniform LDS base, per-lane global src, 16B/lane
typedef const __attribute__((address_space(1))) void gv_t;
typedef __attribute__((address_space(3))) void lv_t;
#define GLOAD16(gp, lp) \
    __builtin_amdgcn_global_load_lds((gv_t*)(gp), (lv_t*)(lp), 16, 0, 0)

// ---------------------------------------------------------------------------
// Kernel A: h = input @ W (fp32 in -> bf16 MFMA), store hT (bf16 [64][8192])
// and per-row scalars s1,s2 (fp32), E=exp(s), F=exp(0.2 s).  (unchanged)
// ---------------------------------------------------------------------------
__global__ __launch_bounds__(256) void gat_h_kernel(
    const float* __restrict__ input,    // [8192][256] fp32
    const float* __restrict__ W,        // [256][64] fp32
    const float* __restrict__ a,        // [128] fp32
    bf16_t* __restrict__ hT,            // [64][8192] bf16 (internal)
    float* __restrict__ s1g, float* __restrict__ e1g, float* __restrict__ f1g,
    float* __restrict__ s2g, float* __restrict__ e2g, float* __restrict__ f2g)
{
    alignas(16) __shared__ bf16_t in_lds[32][264];  // input tile, K contiguous
    alignas(16) __shared__ bf16_t wt_lds[64][264];  // W transposed [f][k]
    __shared__ float h_lds[32][65];                 // h tile fp32 for s1/s2

    const int t  = threadIdx.x;
    const int i0 = blockIdx.x * 32;

    #pragma unroll
    for (int v = 0; v < 8; v++) {
        int u  = v * 256 + t;
        int i  = u >> 6;
        int k4 = (u & 63) * 4;
        floatx4 x = *(const floatx4*)(input + (size_t)(i0 + i) * FIN + k4);
        bf16x4 b;
        #pragma unroll
        for (int e = 0; e < 4; e++) b[e] = (bf16_t)x[e];
        *(bf16x4*)(&in_lds[i][k4]) = b;
    }
    #pragma unroll
    for (int v = 0; v < 16; v++) {
        int u  = v * 256 + t;
        int k  = u >> 4;
        int f4 = (u & 15) * 4;
        floatx4 wv = *(const floatx4*)(W + k * FOUT + f4);
        #pragma unroll
        for (int e = 0; e < 4; e++) wt_lds[f4 + e][k] = (bf16_t)wv[e];
    }
    __syncthreads();

    const int wave = t >> 6;
    const int lane = t & 63;
    const int i16  = (wave & 1) * 16;
    const int f32  = (wave >> 1) * 32;
    const int lm   = lane & 15;
    const int lq   = lane >> 4;

    floatx4 acc0 = {0.f, 0.f, 0.f, 0.f};
    floatx4 acc1 = {0.f, 0.f, 0.f, 0.f};
    #pragma unroll
    for (int ks = 0; ks < 8; ks++) {
        int ko = ks * 32 + lq * 8;
        bf16x8 af = *(const bf16x8*)(&in_lds[i16 + lm][ko]);
        bf16x8 b0 = *(const bf16x8*)(&wt_lds[f32 + lm][ko]);
        bf16x8 b1 = *(const bf16x8*)(&wt_lds[f32 + 16 + lm][ko]);
        acc0 = __builtin_amdgcn_mfma_f32_16x16x32_bf16(af, b0, acc0, 0, 0, 0);
        acc1 = __builtin_amdgcn_mfma_f32_16x16x32_bf16(af, b1, acc1, 0, 0, 0);
    }

    #pragma unroll
    for (int c = 0; c < 2; c++) {
        floatx4 acc = c ? acc1 : acc0;
        int f  = f32 + c * 16 + lm;
        int ib = i0 + i16 + lq * 4;
        bf16x4 hp;
        #pragma unroll
        for (int r = 0; r < 4; r++) hp[r] = (bf16_t)acc[r];
        *(bf16x4*)(hT + (size_t)f * NN + ib) = hp;
    }
    #pragma unroll
    for (int c = 0; c < 2; c++) {
        floatx4 acc = c ? acc1 : acc0;
        #pragma unroll
        for (int r = 0; r < 4; r++)
            h_lds[i16 + lq * 4 + r][f32 + c * 16 + lm] = acc[r];
    }
    __syncthreads();

    if (t < 64) {
        int r   = t & 31;
        int sel = t >> 5;
        const float* av = a + sel * FOUT;
        float s = 0.f;
        #pragma unroll 8
        for (int f = 0; f < FOUT; f++) s += h_lds[r][f] * av[f];
        int gi = i0 + r;
        float E = expf(s);
        float F = expf(GAT_ALPHA * s);
        if (sel == 0) { s1g[gi] = s; e1g[gi] = E; f1g[gi] = F; }
        else          { s2g[gi] = s; e2g[gi] = E; f2g[gi] = F; }
    }
}

// ---------------------------------------------------------------------------
// Kernel B: pipelined LDS attention+aggregation.
//  - block = 256 thr (4 waves), 32 i-rows, JS=512 j-slice, chunks of 64 j
//  - coalesced global_load_lds staging of adj[32][64] + hT[64][64], dbuf
//  - XOR-16B-granule swizzle (row&7) applied on global SOURCE (linear LDS
//    dest, rule #21) so fragment ds_read_b128s are ~2-way conflict (free)
//  - counted s_waitcnt vmcnt(4) + raw s_barrier: next-chunk loads stay in
//    flight across barriers (no vmcnt(0) drain)
//  - w computed in-register per lane straight into A-fragment layout
//  - rowsum via MFMA against all-ones B fragment (wf==0 waves only)
// LDS = 36 KB -> 4 blocks/CU, 16 waves/CU.
// ---------------------------------------------------------------------------
__global__ __launch_bounds__(256, 4) void gat_att_kernel(
    const int* __restrict__ adj,        // [8192][8192] int32
    const bf16_t* __restrict__ hT,      // [64][8192] bf16
    const float* __restrict__ e1g, const float* __restrict__ f1g,
    const float* __restrict__ e2g, const float* __restrict__ f2g,
    float* __restrict__ pacc,           // [NSLICE][8192][64] fp32
    float* __restrict__ prs)            // [NSLICE][8192] fp32
{
    __shared__ int    adjL[2][32][64];          // 16 KB (swizzled layout)
    alignas(16) __shared__ bf16_t htL[2][64][64]; // 16 KB (swizzled layout)
    __shared__ float  e2l[JS], f2l[JS];         // 4 KB

    const int t     = threadIdx.x;
    const int i0    = blockIdx.x * 32;
    const int slice = blockIdx.y;
    const int jbase = slice * JS;

    const int wave = t >> 6;
    const int lane = t & 63;
    const int lm   = lane & 15;
    const int lq   = lane >> 4;
    const int wm   = wave & 1;          // i-tile 0/1
    const int wf   = wave >> 1;         // f-half 0/1
    const int xm   = lm & 7;            // XOR swizzle mask (= row&7 = f&7)

    // ---- prologue: stage e2/f2 slice (1 instr/wave, linear) ----
    {
        const float* src = (wave & 2) ? f2g : e2g;
        float*       dst = (wave & 2) ? f2l : e2l;
        int off = (wave & 1) * 256;
        GLOAD16(src + jbase + off + lane * 4, dst + off);
    }

    // ---- staging: 4 global_load_lds per wave per chunk ----
    auto stage = [&](int b, int c) {
        const int jg = jbase + c * 64;
        #pragma unroll
        for (int h = 0; h < 2; h++) {          // adj rows wave*8 .. +7
            int r0 = wave * 8 + h * 4;
            int i  = r0 + (lane >> 4);
            int gl = (lane & 15) ^ (i & 7);    // inverse swizzle on source
            GLOAD16(adj + (size_t)(i0 + i) * NN + jg + gl * 4,
                    &adjL[b][r0][0]);
        }
        #pragma unroll
        for (int h = 0; h < 2; h++) {          // hT rows wave*16 .. +15
            int f0 = wave * 16 + h * 8;
            int f  = f0 + (lane >> 3);
            int gl = (lane & 7) ^ (f & 7);
            GLOAD16(hT + (size_t)f * NN + jg + gl * 8,
                    &htL[b][f0][0]);
        }
    };

    stage(0, 0);
    stage(1, 1);

    const int   row = i0 + wm * 16 + lm;
    const float E1  = e1g[row];
    const float F1  = f1g[row];

    floatx4 acc0 = {0.f,0.f,0.f,0.f}, acc1 = {0.f,0.f,0.f,0.f};
    floatx4 accR = {0.f,0.f,0.f,0.f};
    bf16x8 ones;
    #pragma unroll
    for (int e = 0; e < 8; e++) ones[e] = (bf16_t)1.0f;

    #pragma unroll
    for (int c = 0; c < NCH; c++) {
        const int b = c & 1;
        // wait own chunk-c loads (chunk c+1's 4 may stay in flight)
        if (c + 1 < NCH) asm volatile("s_waitcnt vmcnt(4)" ::: "memory");
        else             asm volatile("s_waitcnt vmcnt(0)" ::: "memory");
        __builtin_amdgcn_s_barrier();          // all waves' chunk c visible
        asm volatile("" ::: "memory");

        const char* aB = (const char*)&adjL[b][wm * 16 + lm][0];
        const char* hB = (const char*)&htL[b][0][0];
        const int   j0 = c * 64;
        #pragma unroll
        for (int ks = 0; ks < 2; ks++) {
            intx4 a0 = *(const intx4*)(aB + (((ks * 8 + lq * 2 + 0) ^ xm) << 4));
            intx4 a1 = *(const intx4*)(aB + (((ks * 8 + lq * 2 + 1) ^ xm) << 4));
            int jo = j0 + ks * 32 + lq * 8;
            floatx4 e2a = *(const floatx4*)(&e2l[jo]);
            floatx4 e2b = *(const floatx4*)(&e2l[jo + 4]);
            floatx4 f2a = *(const floatx4*)(&f2l[jo]);
            floatx4 f2b = *(const floatx4*)(&f2l[jo + 4]);
            bf16x8 frag;
            #pragma unroll
            for (int e = 0; e < 4; e++) {
                float w0 = fmaxf(E1 * e2a[e], F1 * f2a[e]);
                frag[e]     = (bf16_t)((a0[e] > 0) ? w0 : 0.f);
                float w1 = fmaxf(E1 * e2b[e], F1 * f2b[e]);
                frag[e + 4] = (bf16_t)((a1[e] > 0) ? w1 : 0.f);
            }
            int gh = ((ks * 4 + lq) ^ xm) << 4;
            bf16x8 b0 = *(const bf16x8*)(hB + (wf * 32 + lm) * 128 + gh);
            bf16x8 b1 = *(const bf16x8*)(hB + (wf * 32 + 16 + lm) * 128 + gh);
            acc0 = __builtin_amdgcn_mfma_f32_16x16x32_bf16(frag, b0, acc0, 0, 0, 0);
            acc1 = __builtin_amdgcn_mfma_f32_16x16x32_bf16(frag, b1, acc1, 0, 0, 0);
            if (wf == 0)
                accR = __builtin_amdgcn_mfma_f32_16x16x32_bf16(frag, ones, accR, 0, 0, 0);
        }

        asm volatile("" ::: "memory");
        __builtin_amdgcn_s_barrier();          // all waves done reading buf b
        asm volatile("" ::: "memory");
        if (c + 2 < NCH) stage(b, c + 2);
    }

    // ---- rowsum write (wf==0 waves; all lm lanes identical -> lm==0) ----
    if (wf == 0 && lm == 0) {
        #pragma unroll
        for (int r = 0; r < 4; r++)
            prs[(size_t)slice * NN + i0 + wm * 16 + lq * 4 + r] = accR[r];
    }

    // ---- partial acc write: D layout col = lm, row = lq*4+r ----
    float* pa = pacc + (size_t)slice * NN * FOUT
                     + (size_t)(i0 + wm * 16) * FOUT;
    #pragma unroll
    for (int ft = 0; ft < 2; ft++) {
        floatx4 acc = ft ? acc1 : acc0;
        #pragma unroll
        for (int r = 0; r < 4; r++)
            pa[(size_t)(lq * 4 + r) * FOUT + wf * 32 + ft * 16 + lm] = acc[r];
    }
}

// ---------------------------------------------------------------------------
// Kernel C: combine NSLICE partials, normalize, ELU, store fp32 output.
// ---------------------------------------------------------------------------
__global__ __launch_bounds__(256) void gat_combine_kernel(
    const float* __restrict__ pacc,     // [NSLICE][8192][64]
    const float* __restrict__ prs,      // [NSLICE][8192]
    float* __restrict__ out)            // [8192][64]
{
    int idx = blockIdx.x * 256 + threadIdx.x;
    int i   = idx >> 4;
    floatx4 s = {0.f, 0.f, 0.f, 0.f};
    float rs  = 0.f;
    #pragma unroll
    for (int p = 0; p < NSLICE; p++) {
        floatx4 v = *(const floatx4*)(pacc + (size_t)p * NN * FOUT + (size_t)idx * 4);
        s += v;
        rs += prs[p * NN + i];
    }
    float rinv = (rs > 0.f) ? 1.0f / rs : 0.f;
    floatx4 r;
    #pragma unroll
    for (int e = 0; e < 4; e++) {
        float x = s[e] * rinv;
        r[e] = (x > 0.f) ? x : (expf(x) - 1.0f);
    }
    *(floatx4*)(out + (size_t)idx * 4) = r;
}

// ---------------------------------------------------------------------------
extern "C" void kernel_launch(void* const* d_in, const int* in_sizes, int n_in,
                              void* d_out, int out_size, void* d_ws, size_t ws_size,
                              hipStream_t stream) {
    const float* input = (const float*)d_in[0];     // [8192][256] fp32
    const int*   adj   = (const int*)d_in[1];       // [8192][8192] int32
    const float* W     = (const float*)d_in[2];     // [256][64] fp32
    const float* a     = (const float*)d_in[3];     // [128] fp32
    float*       out   = (float*)d_out;             // [8192][64] fp32

    char* ws = (char*)d_ws;
    bf16_t* hT  = (bf16_t*)ws;                      // 64*8192*2 = 1 MiB
    float*  s1g = (float*)(ws + (1 << 20));
    float*  e1g = s1g + NN;
    float*  f1g = e1g + NN;
    float*  s2g = f1g + NN;
    float*  e2g = s2g + NN;
    float*  f2g = e2g + NN;
    float*  pacc = f2g + NN;                        // NSLICE*8192*64 fp32 = 32 MiB
    float*  prs  = pacc + (size_t)NSLICE * NN * FOUT;  // NSLICE*8192 fp32

    gat_h_kernel<<<NN / 32, 256, 0, stream>>>(input, W, a, hT,
                                              s1g, e1g, f1g, s2g, e2g, f2g);
    dim3 gridB(NN / 32, NSLICE);
    gat_att_kernel<<<gridB, 256, 0, stream>>>(adj, hT, e1g, f1g, e2g, f2g,
                                              pacc, prs);
    gat_combine_kernel<<<NN * FOUT / 4 / 256, 256, 0, stream>>>(pacc, prs, out);
}